// Round 1
// baseline (301.150 us; speedup 1.0000x reference)
//
#include <hip/hip_runtime.h>

typedef __bf16 bf16x8 __attribute__((ext_vector_type(8)));
typedef float  f32x4  __attribute__((ext_vector_type(4)));
typedef unsigned long long u64;

#define MFMA(a, b, c) __builtin_amdgcn_mfma_f32_16x16x32_bf16((a), (b), (c), 0, 0, 0)

__global__ __launch_bounds__(256, 4) void miniemb_kernel(
    const float* __restrict__ windows,
    const float* __restrict__ W1, const float* __restrict__ b1,
    const float* __restrict__ W2, const float* __restrict__ b2,
    const float* __restrict__ W3, const float* __restrict__ b3,
    float* __restrict__ out)
{
    // LDS total = 24576 + 16384 = 40960 B -> exactly 4 blocks/CU (was 51200 -> 3).
    __shared__ float relbuf[48 * 128];   // XOR-swizzled: word = t*128 + (p ^ (t&31))
    __shared__ uint4 w3lds[16][64];      // W3 B-frags; first 2 KiB doubles as pts4 in ph1-2

    float (*pts4)[4] = reinterpret_cast<float(*)[4]>(&w3lds[0][0]);

    const int m    = blockIdx.x;
    const int tid  = threadIdx.x;
    const int w    = tid >> 6;
    const int lane = tid & 63;
    const int g    = lane >> 4;
    const int ln   = lane & 15;

    // ---- phase 0: stage pts4 (x,y,z,|p|^2) -- W3 fill deferred to after phase 2 ----
    const float* wm = windows + (size_t)m * 128 * 3;
    if (tid < 128) {
        float x = wm[tid * 3], y = wm[tid * 3 + 1], z = wm[tid * 3 + 2];
        float s = __fadd_rn(__fadd_rn(__fmul_rn(x, x), __fmul_rn(y, y)),
                            __fmul_rn(z, z));
        f32x4 P = {x, y, z, s};
        *(f32x4*)&pts4[tid][0] = P;
    }
    __syncthreads();

    // ---- phase 1: kNN scan, 2 threads per point, sorted u64 keys kept in registers ----
    const int k = tid >> 1;      // point
    const int h = tid & 1;       // half
    f32x4 Q = *(const f32x4*)&pts4[k][0];
    u64 bd[16];
    #pragma unroll
    for (int t = 0; t < 16; ++t) bd[t] = ~0ull;
    #pragma unroll 1
    for (int jj = 0; jj < 64; ++jj) {
        const int j = (h << 6) + jj;
        f32x4 P = *(const f32x4*)&pts4[j][0];
        // np-exact d2 (bit-identical to the proven path)
        float dot = __fadd_rn(__fadd_rn(__fmul_rn(Q.x, P.x),
                                        __fmul_rn(Q.y, P.y)),
                              __fmul_rn(Q.z, P.z));
        float dd = __fsub_rn(__fadd_rn(Q.w, P.w), __fmul_rn(2.0f, dot));
        unsigned u = __float_as_uint(dd);
        unsigned key32 = u ^ (((unsigned)(((int)u) >> 31)) | 0x80000000u);
        u64 kk = ((u64)key32 << 32) | (unsigned)j;
        #pragma unroll
        for (int t = 0; t < 16; ++t) {
            bool sw = kk < bd[t];
            u64 mn = sw ? kk : bd[t];
            u64 mx = sw ? bd[t] : kk;
            bd[t] = mn; kk = mx;
        }
    }

    // ---- phase 2: lane-pair merge in registers, normalize, write rel ----
    // Partner's sorted list via shuffle (lanes 2j <-> 2j+1). No barrier needed: same wave.
    u64 oth[16];
    #pragma unroll
    for (int i = 0; i < 16; ++i) oth[i] = __shfl_xor(bd[i], 1);

    // Keys embed the global index -> no ties -> strict < is exact for BOTH lanes:
    //  even (own=A): A[i] in top16  iff A[i] < B[15-i]
    //  odd  (own=B): B[i] in top16  iff B[i] < A[15-i]
    // Both selected sets are prefixes; cntE + cntO == 16.
    unsigned msk = 0;
    #pragma unroll
    for (int i = 0; i < 16; ++i)
        msk |= (bd[i] < oth[15 - i]) ? (1u << i) : 0u;
    const int cnt   = __popc(msk);
    const int rbase = h ? (16 - cnt) : 0;   // A rows: 0..cA-1, B rows: cA..15

    // scale = max norm over selected = sqrt(max d2)  (sqrtf monotone -> bit-identical)
    float m2 = 0.0f;
    #pragma unroll
    for (int i = 0; i < 16; ++i) {
        if (i < cnt) {
            f32x4 P = *(const f32x4*)&pts4[(unsigned)bd[i] & 127u][0];
            float dx = P.x - Q.x, dy = P.y - Q.y, dz = P.z - Q.z;
            m2 = fmaxf(m2, dx * dx + dy * dy + dz * dz);
        }
    }
    m2 = fmaxf(m2, __shfl_xor(m2, 1));
    const float inv = 1.0f / fmaxf(sqrtf(m2), 1e-8f);

    #pragma unroll
    for (int i = 0; i < 16; ++i) {
        if (i < cnt) {
            f32x4 P = *(const f32x4*)&pts4[(unsigned)bd[i] & 127u][0];
            const int t0 = (rbase + i) * 3;
            relbuf[(t0 + 0) * 128 + (k ^ ((t0 + 0) & 31))] = (P.x - Q.x) * inv;
            relbuf[(t0 + 1) * 128 + (k ^ ((t0 + 1) & 31))] = (P.y - Q.y) * inv;
            relbuf[(t0 + 2) * 128 + (k ^ ((t0 + 2) & 31))] = (P.z - Q.z) * inv;
        }
    }
    __syncthreads();   // all pts4 reads done -> safe to overwrite with W3 frags

    // ---- phase 2b: fill w3lds (overwrites the pts4 overlay region) ----
    #pragma unroll
    for (int q = 0; q < 4; ++q) {
        const int f = w * 4 + q, n = f >> 1, kb = f & 1;
        bf16x8 v;
        #pragma unroll
        for (int j = 0; j < 8; ++j)
            v[j] = (__bf16)W3[(kb * 32 + g * 8 + j) * 128 + n * 16 + ln];
        w3lds[f][lane] = __builtin_bit_cast(uint4, v);
    }

    // ---- persistent weight fragments (after kNN: caps register pressure) ----
    bf16x8 w2A[4];
    #pragma unroll
    for (int t = 0; t < 4; ++t) {
        const int c = 32 * (t >> 1) + 8 * (ln >> 2) + 4 * (t & 1) + (ln & 3);
        #pragma unroll
        for (int j = 0; j < 8; ++j)
            w2A[t][j] = (__bf16)W2[(g * 8 + j) * 64 + c];
    }
    float b2p[16];
    #pragma unroll
    for (int t = 0; t < 4; ++t)
        #pragma unroll
        for (int r = 0; r < 4; ++r)
            b2p[t * 4 + r] = b2[32 * (t >> 1) + 8 * g + 4 * (t & 1) + r];
    float w1r0[8], w1r1[8], w1r2[8], b1r[8];
    #pragma unroll
    for (int j = 0; j < 8; ++j) {
        const int c = g * 8 + j;
        w1r0[j] = W1[c]; w1r1[j] = W1[32 + c]; w1r2[j] = W1[64 + c]; b1r[j] = b1[c];
    }
    const float b3r0 = b3[(2 * g) * 16 + ln];
    const float b3r1 = b3[(2 * g + 1) * 16 + ln];
    __syncthreads();

    // ---- phase 3: MFMA MLP, 2 points per iteration ----
    // Conflict-free rel reads: bank = p ^ ((3*ln+c)&31), distinct over 16 lanes.
    const float* ra = relbuf + (ln * 3 + 0) * 128;
    const float* rb = relbuf + (ln * 3 + 1) * 128;
    const float* rc = relbuf + (ln * 3 + 2) * 128;
    const int xa = (ln * 3 + 0) & 31;
    const int xb = (ln * 3 + 1) & 31;
    const int xc = (ln * 3 + 2) & 31;

    #pragma unroll 1
    for (int i = 0; i < 16; ++i) {
        const int p0 = w * 32 + 2 * i;
        const int p1 = p0 + 1;
        const float r00 = ra[p0 ^ xa], r01 = rb[p0 ^ xb], r02 = rc[p0 ^ xc];
        const float r10 = ra[p1 ^ xa], r11 = rb[p1 ^ xb], r12 = rc[p1 ^ xc];

        // L1 both points -> B-frag (lane = neighbor), hi/lo split
        bf16x8 a1hi0, a1lo0, a1hi1, a1lo1;
        #pragma unroll
        for (int j = 0; j < 8; ++j) {
            float h0 = fmaf(r02, w1r2[j], fmaf(r01, w1r1[j], fmaf(r00, w1r0[j], b1r[j])));
            h0 = fmaxf(h0, 0.0f);
            __bf16 hh0 = (__bf16)h0;
            a1hi0[j] = hh0; a1lo0[j] = (__bf16)(h0 - (float)hh0);
            float h1v = fmaf(r12, w1r2[j], fmaf(r11, w1r1[j], fmaf(r10, w1r0[j], b1r[j])));
            h1v = fmaxf(h1v, 0.0f);
            __bf16 hh1 = (__bf16)h1v;
            a1hi1[j] = hh1; a1lo1[j] = (__bf16)(h1v - (float)hh1);
        }

        // L2 transposed, both points
        f32x4 c2_0[4], c2_1[4];
        #pragma unroll
        for (int t = 0; t < 4; ++t) {
            f32x4 acc0 = {b2p[t*4+0], b2p[t*4+1], b2p[t*4+2], b2p[t*4+3]};
            f32x4 acc1 = acc0;
            acc0 = MFMA(w2A[t], a1hi0, acc0);
            acc1 = MFMA(w2A[t], a1hi1, acc1);
            acc0 = MFMA(w2A[t], a1lo0, acc0);
            acc1 = MFMA(w2A[t], a1lo1, acc1);
            c2_0[t] = acc0; c2_1[t] = acc1;
        }

        // relu + hi/lo pack into L3 A-frags
        bf16x8 h30a, l30a, h30b, l30b;   // point0: kb=0, kb=1
        bf16x8 h31a, l31a, h31b, l31b;   // point1
        #pragma unroll
        for (int j = 0; j < 8; ++j) {
            const int r = j & 3, ta = j >> 2, tb = 2 + (j >> 2);
            float v0a = fmaxf(c2_0[ta][r], 0.0f);
            __bf16 x0a = (__bf16)v0a; h30a[j] = x0a; l30a[j] = (__bf16)(v0a - (float)x0a);
            float v0b = fmaxf(c2_0[tb][r], 0.0f);
            __bf16 x0b = (__bf16)v0b; h30b[j] = x0b; l30b[j] = (__bf16)(v0b - (float)x0b);
            float v1a = fmaxf(c2_1[ta][r], 0.0f);
            __bf16 x1a = (__bf16)v1a; h31a[j] = x1a; l31a[j] = (__bf16)(v1a - (float)x1a);
            float v1b = fmaxf(c2_1[tb][r], 0.0f);
            __bf16 x1b = (__bf16)v1b; h31b[j] = x1b; l31b[j] = (__bf16)(v1b - (float)x1b);
        }

        // L3: 4 steps x 2 tiles, W3 frags read once, used by both points
        float s0_0 = 0.f, s1_0 = 0.f, s0_1 = 0.f, s1_1 = 0.f;
        #pragma unroll
        for (int nn = 0; nn < 4; ++nn) {
            bf16x8 c0a = __builtin_bit_cast(bf16x8, w3lds[nn * 4 + 0][lane]);
            bf16x8 c0b = __builtin_bit_cast(bf16x8, w3lds[nn * 4 + 1][lane]);
            bf16x8 c1a = __builtin_bit_cast(bf16x8, w3lds[nn * 4 + 2][lane]);
            bf16x8 c1b = __builtin_bit_cast(bf16x8, w3lds[nn * 4 + 3][lane]);
            f32x4 a00 = {0,0,0,0}, a01 = {0,0,0,0}, a10 = {0,0,0,0}, a11 = {0,0,0,0};
            a00 = MFMA(h30a, c0a, a00); a00 = MFMA(h30b, c0b, a00);
            a00 = MFMA(l30a, c0a, a00); a00 = MFMA(l30b, c0b, a00);
            a01 = MFMA(h30a, c1a, a01); a01 = MFMA(h30b, c1b, a01);
            a01 = MFMA(l30a, c1a, a01); a01 = MFMA(l30b, c1b, a01);
            a10 = MFMA(h31a, c0a, a10); a10 = MFMA(h31b, c0b, a10);
            a10 = MFMA(l31a, c0a, a10); a10 = MFMA(l31b, c0b, a10);
            a11 = MFMA(h31a, c1a, a11); a11 = MFMA(h31b, c1b, a11);
            a11 = MFMA(l31a, c1a, a11); a11 = MFMA(l31b, c1b, a11);
            float v00 = fmaxf(fmaxf(a00[0], a00[1]), fmaxf(a00[2], a00[3]));
            v00 = fmaxf(v00, __shfl_xor(v00, 16)); v00 = fmaxf(v00, __shfl_xor(v00, 32));
            float v01 = fmaxf(fmaxf(a01[0], a01[1]), fmaxf(a01[2], a01[3]));
            v01 = fmaxf(v01, __shfl_xor(v01, 16)); v01 = fmaxf(v01, __shfl_xor(v01, 32));
            float v10 = fmaxf(fmaxf(a10[0], a10[1]), fmaxf(a10[2], a10[3]));
            v10 = fmaxf(v10, __shfl_xor(v10, 16)); v10 = fmaxf(v10, __shfl_xor(v10, 32));
            float v11 = fmaxf(fmaxf(a11[0], a11[1]), fmaxf(a11[2], a11[3]));
            v11 = fmaxf(v11, __shfl_xor(v11, 16)); v11 = fmaxf(v11, __shfl_xor(v11, 32));
            if (nn == g) { s0_0 = v00; s1_0 = v01; s0_1 = v10; s1_1 = v11; }
        }
        float* o0 = out + ((size_t)(m * 128 + p0) << 7);
        float* o1 = out + ((size_t)(m * 128 + p1) << 7);
        o0[(2 * g) * 16 + ln]     = s0_0 + b3r0;
        o0[(2 * g + 1) * 16 + ln] = s1_0 + b3r1;
        o1[(2 * g) * 16 + ln]     = s0_1 + b3r0;
        o1[(2 * g + 1) * 16 + ln] = s1_1 + b3r1;
    }
}

extern "C" void kernel_launch(void* const* d_in, const int* in_sizes, int n_in,
                              void* d_out, int out_size, void* d_ws, size_t ws_size,
                              hipStream_t stream) {
    const float* windows = (const float*)d_in[0];
    const float* W1 = (const float*)d_in[1];
    const float* b1 = (const float*)d_in[2];
    const float* W2 = (const float*)d_in[3];
    const float* b2 = (const float*)d_in[4];
    const float* W3 = (const float*)d_in[5];
    const float* b3 = (const float*)d_in[6];
    float* out = (float*)d_out;
    hipLaunchKernelGGL(miniemb_kernel, dim3(1024), dim3(256), 0, stream,
                       windows, W1, b1, W2, b2, W3, b3, out);
}

// Round 2
// 228.076 us; speedup vs baseline: 1.3204x; 1.3204x over previous
//
#include <hip/hip_runtime.h>

typedef __bf16 bf16x8 __attribute__((ext_vector_type(8)));
typedef float  f32x4  __attribute__((ext_vector_type(4)));
typedef unsigned long long u64;

#define MFMA(a, b, c) __builtin_amdgcn_mfma_f32_16x16x32_bf16((a), (b), (c), 0, 0, 0)

// NOTE: plain __launch_bounds__(256). The (256,4) variant made the backend cap
// VGPRs at 64 -> ~690 MB/dispatch of scratch spill traffic (FETCH 604 MB).
// With LDS = 40960 B and VGPR <= 128 the LDS limit alone gives 4 blocks/CU.
__global__ __launch_bounds__(256) void miniemb_kernel(
    const float* __restrict__ windows,
    const float* __restrict__ W1, const float* __restrict__ b1,
    const float* __restrict__ W2, const float* __restrict__ b2,
    const float* __restrict__ W3, const float* __restrict__ b3,
    float* __restrict__ out)
{
    // LDS total = 24576 + 16384 = 40960 B -> 4 blocks/CU (was 51200 -> 3).
    __shared__ float relbuf[48 * 128];   // XOR-swizzled: word = t*128 + (p ^ (t&31))
    __shared__ uint4 w3lds[16][64];      // W3 B-frags; first 2 KiB doubles as pts4 in ph1-2

    float (*pts4)[4] = reinterpret_cast<float(*)[4]>(&w3lds[0][0]);

    const int m    = blockIdx.x;
    const int tid  = threadIdx.x;
    const int w    = tid >> 6;
    const int lane = tid & 63;
    const int g    = lane >> 4;
    const int ln   = lane & 15;

    // ---- phase 0: stage pts4 (x,y,z,|p|^2) -- W3 fill deferred to after phase 2 ----
    const float* wm = windows + (size_t)m * 128 * 3;
    if (tid < 128) {
        float x = wm[tid * 3], y = wm[tid * 3 + 1], z = wm[tid * 3 + 2];
        float s = __fadd_rn(__fadd_rn(__fmul_rn(x, x), __fmul_rn(y, y)),
                            __fmul_rn(z, z));
        f32x4 P = {x, y, z, s};
        *(f32x4*)&pts4[tid][0] = P;
    }
    __syncthreads();

    // ---- phase 1: kNN scan, 2 threads per point, sorted u64 keys kept in registers ----
    const int k = tid >> 1;      // point
    const int h = tid & 1;       // half
    f32x4 Q = *(const f32x4*)&pts4[k][0];
    u64 bd[16];
    #pragma unroll
    for (int t = 0; t < 16; ++t) bd[t] = ~0ull;
    #pragma unroll 1
    for (int jj = 0; jj < 64; ++jj) {
        const int j = (h << 6) + jj;
        f32x4 P = *(const f32x4*)&pts4[j][0];
        // np-exact d2 (bit-identical to the proven path)
        float dot = __fadd_rn(__fadd_rn(__fmul_rn(Q.x, P.x),
                                        __fmul_rn(Q.y, P.y)),
                              __fmul_rn(Q.z, P.z));
        float dd = __fsub_rn(__fadd_rn(Q.w, P.w), __fmul_rn(2.0f, dot));
        unsigned u = __float_as_uint(dd);
        unsigned key32 = u ^ (((unsigned)(((int)u) >> 31)) | 0x80000000u);
        u64 kk = ((u64)key32 << 32) | (unsigned)j;
        #pragma unroll
        for (int t = 0; t < 16; ++t) {
            bool sw = kk < bd[t];
            u64 mn = sw ? kk : bd[t];
            u64 mx = sw ? bd[t] : kk;
            bd[t] = mn; kk = mx;
        }
    }

    // ---- phase 2: lane-pair merge, partner values STREAMED via shuffle ----
    // (no oth[16] array: saves 32 VGPRs at the phase-2 register peak)
    // Keys embed the global index -> no ties -> strict < exact for BOTH lanes:
    //  even (own=A): A[i] in top16 iff A[i] < B[15-i]
    //  odd  (own=B): B[i] in top16 iff B[i] < A[15-i]
    // Selected sets are prefixes; cntE + cntO == 16.
    unsigned msk = 0;
    #pragma unroll
    for (int i = 0; i < 16; ++i) {
        u64 o = __shfl_xor(bd[15 - i], 1);   // partner's bd[15-i]
        msk |= (bd[i] < o) ? (1u << i) : 0u;
    }
    const int cnt   = __popc(msk);
    const int rbase = h ? (16 - cnt) : 0;    // A rows: 0..cA-1, B rows: cA..15

    // scale = max norm over selected = sqrt(max d2)  (sqrtf monotone -> bit-identical)
    float m2 = 0.0f;
    #pragma unroll
    for (int i = 0; i < 16; ++i) {
        if (i < cnt) {
            f32x4 P = *(const f32x4*)&pts4[(unsigned)bd[i] & 127u][0];
            float dx = P.x - Q.x, dy = P.y - Q.y, dz = P.z - Q.z;
            m2 = fmaxf(m2, dx * dx + dy * dy + dz * dz);
        }
    }
    m2 = fmaxf(m2, __shfl_xor(m2, 1));
    const float inv = 1.0f / fmaxf(sqrtf(m2), 1e-8f);

    #pragma unroll
    for (int i = 0; i < 16; ++i) {
        if (i < cnt) {
            f32x4 P = *(const f32x4*)&pts4[(unsigned)bd[i] & 127u][0];
            const int t0 = (rbase + i) * 3;
            relbuf[(t0 + 0) * 128 + (k ^ ((t0 + 0) & 31))] = (P.x - Q.x) * inv;
            relbuf[(t0 + 1) * 128 + (k ^ ((t0 + 1) & 31))] = (P.y - Q.y) * inv;
            relbuf[(t0 + 2) * 128 + (k ^ ((t0 + 2) & 31))] = (P.z - Q.z) * inv;
        }
    }
    __syncthreads();   // all pts4 reads done -> safe to overwrite with W3 frags

    // ---- phase 2b: fill w3lds (overwrites the pts4 overlay region) ----
    #pragma unroll
    for (int q = 0; q < 4; ++q) {
        const int f = w * 4 + q, n = f >> 1, kb = f & 1;
        bf16x8 v;
        #pragma unroll
        for (int j = 0; j < 8; ++j)
            v[j] = (__bf16)W3[(kb * 32 + g * 8 + j) * 128 + n * 16 + ln];
        w3lds[f][lane] = __builtin_bit_cast(uint4, v);
    }

    // ---- persistent weight fragments (after kNN: caps register pressure) ----
    bf16x8 w2A[4];
    #pragma unroll
    for (int t = 0; t < 4; ++t) {
        const int c = 32 * (t >> 1) + 8 * (ln >> 2) + 4 * (t & 1) + (ln & 3);
        #pragma unroll
        for (int j = 0; j < 8; ++j)
            w2A[t][j] = (__bf16)W2[(g * 8 + j) * 64 + c];
    }
    float b2p[16];
    #pragma unroll
    for (int t = 0; t < 4; ++t)
        #pragma unroll
        for (int r = 0; r < 4; ++r)
            b2p[t * 4 + r] = b2[32 * (t >> 1) + 8 * g + 4 * (t & 1) + r];
    float w1r0[8], w1r1[8], w1r2[8], b1r[8];
    #pragma unroll
    for (int j = 0; j < 8; ++j) {
        const int c = g * 8 + j;
        w1r0[j] = W1[c]; w1r1[j] = W1[32 + c]; w1r2[j] = W1[64 + c]; b1r[j] = b1[c];
    }
    const float b3r0 = b3[(2 * g) * 16 + ln];
    const float b3r1 = b3[(2 * g + 1) * 16 + ln];
    __syncthreads();

    // ---- phase 3: MFMA MLP, 2 points per iteration ----
    // Conflict-free rel reads: bank = p ^ ((3*ln+c)&31), distinct over 16 lanes.
    const float* ra = relbuf + (ln * 3 + 0) * 128;
    const float* rb = relbuf + (ln * 3 + 1) * 128;
    const float* rc = relbuf + (ln * 3 + 2) * 128;
    const int xa = (ln * 3 + 0) & 31;
    const int xb = (ln * 3 + 1) & 31;
    const int xc = (ln * 3 + 2) & 31;

    #pragma unroll 1
    for (int i = 0; i < 16; ++i) {
        const int p0 = w * 32 + 2 * i;
        const int p1 = p0 + 1;
        const float r00 = ra[p0 ^ xa], r01 = rb[p0 ^ xb], r02 = rc[p0 ^ xc];
        const float r10 = ra[p1 ^ xa], r11 = rb[p1 ^ xb], r12 = rc[p1 ^ xc];

        // L1 both points -> B-frag (lane = neighbor), hi/lo split
        bf16x8 a1hi0, a1lo0, a1hi1, a1lo1;
        #pragma unroll
        for (int j = 0; j < 8; ++j) {
            float h0 = fmaf(r02, w1r2[j], fmaf(r01, w1r1[j], fmaf(r00, w1r0[j], b1r[j])));
            h0 = fmaxf(h0, 0.0f);
            __bf16 hh0 = (__bf16)h0;
            a1hi0[j] = hh0; a1lo0[j] = (__bf16)(h0 - (float)hh0);
            float h1v = fmaf(r12, w1r2[j], fmaf(r11, w1r1[j], fmaf(r10, w1r0[j], b1r[j])));
            h1v = fmaxf(h1v, 0.0f);
            __bf16 hh1 = (__bf16)h1v;
            a1hi1[j] = hh1; a1lo1[j] = (__bf16)(h1v - (float)hh1);
        }

        // L2 transposed, both points
        f32x4 c2_0[4], c2_1[4];
        #pragma unroll
        for (int t = 0; t < 4; ++t) {
            f32x4 acc0 = {b2p[t*4+0], b2p[t*4+1], b2p[t*4+2], b2p[t*4+3]};
            f32x4 acc1 = acc0;
            acc0 = MFMA(w2A[t], a1hi0, acc0);
            acc1 = MFMA(w2A[t], a1hi1, acc1);
            acc0 = MFMA(w2A[t], a1lo0, acc0);
            acc1 = MFMA(w2A[t], a1lo1, acc1);
            c2_0[t] = acc0; c2_1[t] = acc1;
        }

        // relu + hi/lo pack into L3 A-frags
        bf16x8 h30a, l30a, h30b, l30b;   // point0: kb=0, kb=1
        bf16x8 h31a, l31a, h31b, l31b;   // point1
        #pragma unroll
        for (int j = 0; j < 8; ++j) {
            const int r = j & 3, ta = j >> 2, tb = 2 + (j >> 2);
            float v0a = fmaxf(c2_0[ta][r], 0.0f);
            __bf16 x0a = (__bf16)v0a; h30a[j] = x0a; l30a[j] = (__bf16)(v0a - (float)x0a);
            float v0b = fmaxf(c2_0[tb][r], 0.0f);
            __bf16 x0b = (__bf16)v0b; h30b[j] = x0b; l30b[j] = (__bf16)(v0b - (float)x0b);
            float v1a = fmaxf(c2_1[ta][r], 0.0f);
            __bf16 x1a = (__bf16)v1a; h31a[j] = x1a; l31a[j] = (__bf16)(v1a - (float)x1a);
            float v1b = fmaxf(c2_1[tb][r], 0.0f);
            __bf16 x1b = (__bf16)v1b; h31b[j] = x1b; l31b[j] = (__bf16)(v1b - (float)x1b);
        }

        // L3: 4 steps x 2 tiles, W3 frags read once, used by both points
        float s0_0 = 0.f, s1_0 = 0.f, s0_1 = 0.f, s1_1 = 0.f;
        #pragma unroll
        for (int nn = 0; nn < 4; ++nn) {
            bf16x8 c0a = __builtin_bit_cast(bf16x8, w3lds[nn * 4 + 0][lane]);
            bf16x8 c0b = __builtin_bit_cast(bf16x8, w3lds[nn * 4 + 1][lane]);
            bf16x8 c1a = __builtin_bit_cast(bf16x8, w3lds[nn * 4 + 2][lane]);
            bf16x8 c1b = __builtin_bit_cast(bf16x8, w3lds[nn * 4 + 3][lane]);
            f32x4 a00 = {0,0,0,0}, a01 = {0,0,0,0}, a10 = {0,0,0,0}, a11 = {0,0,0,0};
            a00 = MFMA(h30a, c0a, a00); a00 = MFMA(h30b, c0b, a00);
            a00 = MFMA(l30a, c0a, a00); a00 = MFMA(l30b, c0b, a00);
            a01 = MFMA(h30a, c1a, a01); a01 = MFMA(h30b, c1b, a01);
            a01 = MFMA(l30a, c1a, a01); a01 = MFMA(l30b, c1b, a01);
            a10 = MFMA(h31a, c0a, a10); a10 = MFMA(h31b, c0b, a10);
            a10 = MFMA(l31a, c0a, a10); a10 = MFMA(l31b, c0b, a10);
            a11 = MFMA(h31a, c1a, a11); a11 = MFMA(h31b, c1b, a11);
            a11 = MFMA(l31a, c1a, a11); a11 = MFMA(l31b, c1b, a11);
            float v00 = fmaxf(fmaxf(a00[0], a00[1]), fmaxf(a00[2], a00[3]));
            v00 = fmaxf(v00, __shfl_xor(v00, 16)); v00 = fmaxf(v00, __shfl_xor(v00, 32));
            float v01 = fmaxf(fmaxf(a01[0], a01[1]), fmaxf(a01[2], a01[3]));
            v01 = fmaxf(v01, __shfl_xor(v01, 16)); v01 = fmaxf(v01, __shfl_xor(v01, 32));
            float v10 = fmaxf(fmaxf(a10[0], a10[1]), fmaxf(a10[2], a10[3]));
            v10 = fmaxf(v10, __shfl_xor(v10, 16)); v10 = fmaxf(v10, __shfl_xor(v10, 32));
            float v11 = fmaxf(fmaxf(a11[0], a11[1]), fmaxf(a11[2], a11[3]));
            v11 = fmaxf(v11, __shfl_xor(v11, 16)); v11 = fmaxf(v11, __shfl_xor(v11, 32));
            if (nn == g) { s0_0 = v00; s1_0 = v01; s0_1 = v10; s1_1 = v11; }
        }
        float* o0 = out + ((size_t)(m * 128 + p0) << 7);
        float* o1 = out + ((size_t)(m * 128 + p1) << 7);
        o0[(2 * g) * 16 + ln]     = s0_0 + b3r0;
        o0[(2 * g + 1) * 16 + ln] = s1_0 + b3r1;
        o1[(2 * g) * 16 + ln]     = s0_1 + b3r0;
        o1[(2 * g + 1) * 16 + ln] = s1_1 + b3r1;
    }
}

extern "C" void kernel_launch(void* const* d_in, const int* in_sizes, int n_in,
                              void* d_out, int out_size, void* d_ws, size_t ws_size,
                              hipStream_t stream) {
    const float* windows = (const float*)d_in[0];
    const float* W1 = (const float*)d_in[1];
    const float* b1 = (const float*)d_in[2];
    const float* W2 = (const float*)d_in[3];
    const float* b2 = (const float*)d_in[4];
    const float* W3 = (const float*)d_in[5];
    const float* b3 = (const float*)d_in[6];
    float* out = (float*)d_out;
    hipLaunchKernelGGL(miniemb_kernel, dim3(1024), dim3(256), 0, stream,
                       windows, W1, b1, W2, b2, W3, b3, out);
}

// Round 6
// 220.241 us; speedup vs baseline: 1.3674x; 1.0356x over previous
//
#include <hip/hip_runtime.h>

typedef __bf16 bf16x8 __attribute__((ext_vector_type(8)));
typedef float  f32x4  __attribute__((ext_vector_type(4)));
typedef unsigned long long u64;

#define MFMA(a, b, c) __builtin_amdgcn_mfma_f32_16x16x32_bf16((a), (b), (c), 0, 0, 0)

// NOTE: plain __launch_bounds__(256). The (256,4) variant made the backend cap
// VGPRs at 64 -> ~690 MB/dispatch of scratch spill traffic.
__global__ __launch_bounds__(256) void miniemb_kernel(
    const float* __restrict__ windows,
    const float* __restrict__ W1, const float* __restrict__ b1,
    const float* __restrict__ W2, const float* __restrict__ b2,
    const float* __restrict__ W3, const float* __restrict__ b3,
    float* __restrict__ out)
{
    // LDS total = 24576 + 16384 = 40960 B.
    __shared__ float relbuf[48 * 128];   // XOR-swizzled: word = t*128 + (p ^ (t&31))
    __shared__ uint4 w3lds[16][64];      // W3 B-frags; first 2 KiB doubles as pts4 in ph1-2

    float (*pts4)[4] = reinterpret_cast<float(*)[4]>(&w3lds[0][0]);

    const int m    = blockIdx.x;
    const int tid  = threadIdx.x;
    const int w    = tid >> 6;
    const int lane = tid & 63;
    const int g    = lane >> 4;
    const int ln   = lane & 15;

    // ---- phase 0: stage pts4 (x,y,z,|p|^2) -- W3 fill deferred to after phase 2 ----
    const float* wm = windows + (size_t)m * 128 * 3;
    if (tid < 128) {
        float x = wm[tid * 3], y = wm[tid * 3 + 1], z = wm[tid * 3 + 2];
        float s = __fadd_rn(__fadd_rn(__fmul_rn(x, x), __fmul_rn(y, y)),
                            __fmul_rn(z, z));
        f32x4 P = {x, y, z, s};
        *(f32x4*)&pts4[tid][0] = P;
    }
    __syncthreads();

    // ---- phase 1: kNN scan, 2 threads per point, sorted insert (breadth-wise) ----
    // Same selection SEMANTICS as the proven serial CAS chain (sorted-insert,
    // drop max) -- re-expressed as 16 INDEPENDENT compares + 16 independent
    // selects per candidate:
    //   ct[t] = bd[t] < kk          (bd sorted  =>  ct[t] <=> t < insert_pos)
    //   bd[t] = ct[t] ? bd[t] : (ct[t-1] ? kk : bd[t-1])   (t = 15..0)
    // Verified equal to the chain on paper ({1,3} insert 0/2/5). Dep depth per
    // candidate drops ~32 -> ~3 at identical instruction count.
    const int k = tid >> 1;      // point
    const int h = tid & 1;       // half
    f32x4 Q = *(const f32x4*)&pts4[k][0];
    u64 bd[16];
    #pragma unroll
    for (int t = 0; t < 16; ++t) bd[t] = ~0ull;
    #pragma unroll 1
    for (int jj = 0; jj < 64; ++jj) {
        const int j = (h << 6) + jj;
        f32x4 P = *(const f32x4*)&pts4[j][0];
        // np-exact d2 (bit-identical to the round-2 proven path)
        float dot = __fadd_rn(__fadd_rn(__fmul_rn(Q.x, P.x),
                                        __fmul_rn(Q.y, P.y)),
                              __fmul_rn(Q.z, P.z));
        float dd = __fsub_rn(__fadd_rn(Q.w, P.w), __fmul_rn(2.0f, dot));
        unsigned u = __float_as_uint(dd);
        unsigned key32 = u ^ (((unsigned)(((int)u) >> 31)) | 0x80000000u);
        u64 kk = ((u64)key32 << 32) | (unsigned)j;
        bool ct[16];
        #pragma unroll
        for (int t = 0; t < 16; ++t) ct[t] = bd[t] < kk;
        #pragma unroll
        for (int t = 15; t >= 1; --t)
            bd[t] = ct[t] ? bd[t] : (ct[t - 1] ? kk : bd[t - 1]);
        bd[0] = ct[0] ? bd[0] : kk;
    }

    // ---- phase 2: lane-pair merge, partner values STREAMED via shuffle ----
    // Keys embed the global index -> no ties -> strict < exact for BOTH lanes:
    //  even (own=A): A[i] in top16 iff A[i] < B[15-i]
    //  odd  (own=B): B[i] in top16 iff B[i] < A[15-i]
    // Selected sets are prefixes; cntE + cntO == 16.
    unsigned msk = 0;
    #pragma unroll
    for (int i = 0; i < 16; ++i) {
        u64 o = __shfl_xor(bd[15 - i], 1);   // partner's bd[15-i]
        msk |= (bd[i] < o) ? (1u << i) : 0u;
    }
    const int cnt   = __popc(msk);
    const int rbase = h ? (16 - cnt) : 0;    // A rows: 0..cA-1, B rows: cA..15

    // scale = max norm over selected = sqrt(max d2)  (sqrtf monotone -> bit-identical)
    float m2 = 0.0f;
    #pragma unroll
    for (int i = 0; i < 16; ++i) {
        if (i < cnt) {
            f32x4 P = *(const f32x4*)&pts4[(unsigned)bd[i] & 127u][0];
            float dx = P.x - Q.x, dy = P.y - Q.y, dz = P.z - Q.z;
            m2 = fmaxf(m2, dx * dx + dy * dy + dz * dz);
        }
    }
    m2 = fmaxf(m2, __shfl_xor(m2, 1));
    const float inv = 1.0f / fmaxf(sqrtf(m2), 1e-8f);

    #pragma unroll
    for (int i = 0; i < 16; ++i) {
        if (i < cnt) {
            f32x4 P = *(const f32x4*)&pts4[(unsigned)bd[i] & 127u][0];
            const int t0 = (rbase + i) * 3;
            relbuf[(t0 + 0) * 128 + (k ^ ((t0 + 0) & 31))] = (P.x - Q.x) * inv;
            relbuf[(t0 + 1) * 128 + (k ^ ((t0 + 1) & 31))] = (P.y - Q.y) * inv;
            relbuf[(t0 + 2) * 128 + (k ^ ((t0 + 2) & 31))] = (P.z - Q.z) * inv;
        }
    }
    __syncthreads();   // all pts4 reads done -> safe to overwrite with W3 frags

    // ---- phase 2b: fill w3lds (overwrites the pts4 overlay region) ----
    #pragma unroll
    for (int q = 0; q < 4; ++q) {
        const int f = w * 4 + q, n = f >> 1, kb = f & 1;
        bf16x8 v;
        #pragma unroll
        for (int j = 0; j < 8; ++j)
            v[j] = (__bf16)W3[(kb * 32 + g * 8 + j) * 128 + n * 16 + ln];
        w3lds[f][lane] = __builtin_bit_cast(uint4, v);
    }

    // ---- persistent weight fragments (after kNN: caps register pressure) ----
    bf16x8 w2A[4];
    #pragma unroll
    for (int t = 0; t < 4; ++t) {
        const int c = 32 * (t >> 1) + 8 * (ln >> 2) + 4 * (t & 1) + (ln & 3);
        #pragma unroll
        for (int j = 0; j < 8; ++j)
            w2A[t][j] = (__bf16)W2[(g * 8 + j) * 64 + c];
    }
    float b2p[16];
    #pragma unroll
    for (int t = 0; t < 4; ++t)
        #pragma unroll
        for (int r = 0; r < 4; ++r)
            b2p[t * 4 + r] = b2[32 * (t >> 1) + 8 * g + 4 * (t & 1) + r];
    float w1r0[8], w1r1[8], w1r2[8], b1r[8];
    #pragma unroll
    for (int j = 0; j < 8; ++j) {
        const int c = g * 8 + j;
        w1r0[j] = W1[c]; w1r1[j] = W1[32 + c]; w1r2[j] = W1[64 + c]; b1r[j] = b1[c];
    }
    const float b3r0 = b3[(2 * g) * 16 + ln];
    const float b3r1 = b3[(2 * g + 1) * 16 + ln];
    __syncthreads();

    // ---- phase 3: MFMA MLP, 2 points per iteration ----
    // Conflict-free rel reads: bank = p ^ ((3*ln+c)&31), distinct over 16 lanes.
    const float* ra = relbuf + (ln * 3 + 0) * 128;
    const float* rb = relbuf + (ln * 3 + 1) * 128;
    const float* rc = relbuf + (ln * 3 + 2) * 128;
    const int xa = (ln * 3 + 0) & 31;
    const int xb = (ln * 3 + 1) & 31;
    const int xc = (ln * 3 + 2) & 31;

    #pragma unroll 1
    for (int i = 0; i < 16; ++i) {
        const int p0 = w * 32 + 2 * i;
        const int p1 = p0 + 1;
        const float r00 = ra[p0 ^ xa], r01 = rb[p0 ^ xb], r02 = rc[p0 ^ xc];
        const float r10 = ra[p1 ^ xa], r11 = rb[p1 ^ xb], r12 = rc[p1 ^ xc];

        // L1 both points -> B-frag (lane = neighbor), hi/lo split
        bf16x8 a1hi0, a1lo0, a1hi1, a1lo1;
        #pragma unroll
        for (int j = 0; j < 8; ++j) {
            float h0 = fmaf(r02, w1r2[j], fmaf(r01, w1r1[j], fmaf(r00, w1r0[j], b1r[j])));
            h0 = fmaxf(h0, 0.0f);
            __bf16 hh0 = (__bf16)h0;
            a1hi0[j] = hh0; a1lo0[j] = (__bf16)(h0 - (float)hh0);
            float h1v = fmaf(r12, w1r2[j], fmaf(r11, w1r1[j], fmaf(r10, w1r0[j], b1r[j])));
            h1v = fmaxf(h1v, 0.0f);
            __bf16 hh1 = (__bf16)h1v;
            a1hi1[j] = hh1; a1lo1[j] = (__bf16)(h1v - (float)hh1);
        }

        // L2 transposed, both points
        f32x4 c2_0[4], c2_1[4];
        #pragma unroll
        for (int t = 0; t < 4; ++t) {
            f32x4 acc0 = {b2p[t*4+0], b2p[t*4+1], b2p[t*4+2], b2p[t*4+3]};
            f32x4 acc1 = acc0;
            acc0 = MFMA(w2A[t], a1hi0, acc0);
            acc1 = MFMA(w2A[t], a1hi1, acc1);
            acc0 = MFMA(w2A[t], a1lo0, acc0);
            acc1 = MFMA(w2A[t], a1lo1, acc1);
            c2_0[t] = acc0; c2_1[t] = acc1;
        }

        // relu + hi/lo pack into L3 A-frags
        bf16x8 h30a, l30a, h30b, l30b;   // point0: kb=0, kb=1
        bf16x8 h31a, l31a, h31b, l31b;   // point1
        #pragma unroll
        for (int j = 0; j < 8; ++j) {
            const int r = j & 3, ta = j >> 2, tb = 2 + (j >> 2);
            float v0a = fmaxf(c2_0[ta][r], 0.0f);
            __bf16 x0a = (__bf16)v0a; h30a[j] = x0a; l30a[j] = (__bf16)(v0a - (float)x0a);
            float v0b = fmaxf(c2_0[tb][r], 0.0f);
            __bf16 x0b = (__bf16)v0b; h30b[j] = x0b; l30b[j] = (__bf16)(v0b - (float)x0b);
            float v1a = fmaxf(c2_1[ta][r], 0.0f);
            __bf16 x1a = (__bf16)v1a; h31a[j] = x1a; l31a[j] = (__bf16)(v1a - (float)x1a);
            float v1b = fmaxf(c2_1[tb][r], 0.0f);
            __bf16 x1b = (__bf16)v1b; h31b[j] = x1b; l31b[j] = (__bf16)(v1b - (float)x1b);
        }

        // L3: 4 steps x 2 tiles, W3 frags read once, used by both points
        float s0_0 = 0.f, s1_0 = 0.f, s0_1 = 0.f, s1_1 = 0.f;
        #pragma unroll
        for (int nn = 0; nn < 4; ++nn) {
            bf16x8 c0a = __builtin_bit_cast(bf16x8, w3lds[nn * 4 + 0][lane]);
            bf16x8 c0b = __builtin_bit_cast(bf16x8, w3lds[nn * 4 + 1][lane]);
            bf16x8 c1a = __builtin_bit_cast(bf16x8, w3lds[nn * 4 + 2][lane]);
            bf16x8 c1b = __builtin_bit_cast(bf16x8, w3lds[nn * 4 + 3][lane]);
            f32x4 a00 = {0,0,0,0}, a01 = {0,0,0,0}, a10 = {0,0,0,0}, a11 = {0,0,0,0};
            a00 = MFMA(h30a, c0a, a00); a00 = MFMA(h30b, c0b, a00);
            a00 = MFMA(l30a, c0a, a00); a00 = MFMA(l30b, c0b, a00);
            a01 = MFMA(h30a, c1a, a01); a01 = MFMA(h30b, c1b, a01);
            a01 = MFMA(l30a, c1a, a01); a01 = MFMA(l30b, c1b, a01);
            a10 = MFMA(h31a, c0a, a10); a10 = MFMA(h31b, c0b, a10);
            a10 = MFMA(l31a, c0a, a10); a10 = MFMA(l31b, c0b, a10);
            a11 = MFMA(h31a, c1a, a11); a11 = MFMA(h31b, c1b, a11);
            a11 = MFMA(l31a, c1a, a11); a11 = MFMA(l31b, c1b, a11);
            float v00 = fmaxf(fmaxf(a00[0], a00[1]), fmaxf(a00[2], a00[3]));
            v00 = fmaxf(v00, __shfl_xor(v00, 16)); v00 = fmaxf(v00, __shfl_xor(v00, 32));
            float v01 = fmaxf(fmaxf(a01[0], a01[1]), fmaxf(a01[2], a01[3]));
            v01 = fmaxf(v01, __shfl_xor(v01, 16)); v01 = fmaxf(v01, __shfl_xor(v01, 32));
            float v10 = fmaxf(fmaxf(a10[0], a10[1]), fmaxf(a10[2], a10[3]));
            v10 = fmaxf(v10, __shfl_xor(v10, 16)); v10 = fmaxf(v10, __shfl_xor(v10, 32));
            float v11 = fmaxf(fmaxf(a11[0], a11[1]), fmaxf(a11[2], a11[3]));
            v11 = fmaxf(v11, __shfl_xor(v11, 16)); v11 = fmaxf(v11, __shfl_xor(v11, 32));
            if (nn == g) { s0_0 = v00; s1_0 = v01; s0_1 = v10; s1_1 = v11; }
        }
        float* o0 = out + ((size_t)(m * 128 + p0) << 7);
        float* o1 = out + ((size_t)(m * 128 + p1) << 7);
        o0[(2 * g) * 16 + ln]     = s0_0 + b3r0;
        o0[(2 * g + 1) * 16 + ln] = s1_0 + b3r1;
        o1[(2 * g) * 16 + ln]     = s0_1 + b3r0;
        o1[(2 * g + 1) * 16 + ln] = s1_1 + b3r1;
    }
}

extern "C" void kernel_launch(void* const* d_in, const int* in_sizes, int n_in,
                              void* d_out, int out_size, void* d_ws, size_t ws_size,
                              hipStream_t stream) {
    const float* windows = (const float*)d_in[0];
    const float* W1 = (const float*)d_in[1];
    const float* b1 = (const float*)d_in[2];
    const float* W2 = (const float*)d_in[3];
    const float* b2 = (const float*)d_in[4];
    const float* W3 = (const float*)d_in[5];
    const float* b3 = (const float*)d_in[6];
    float* out = (float*)d_out;
    hipLaunchKernelGGL(miniemb_kernel, dim3(1024), dim3(256), 0, stream,
                       windows, W1, b1, W2, b2, W3, b3, out);
}

// Round 7
// 214.722 us; speedup vs baseline: 1.4025x; 1.0257x over previous
//
#include <hip/hip_runtime.h>

typedef __bf16 bf16x8 __attribute__((ext_vector_type(8)));
typedef __bf16 bf16x2 __attribute__((ext_vector_type(2)));
typedef float  f32x4  __attribute__((ext_vector_type(4)));
typedef float  f32x2  __attribute__((ext_vector_type(2)));
typedef unsigned long long u64;

#define MFMA(a, b, c) __builtin_amdgcn_mfma_f32_16x16x32_bf16((a), (b), (c), 0, 0, 0)

// Packed fp32 helpers -> v_pk_fma_f32 / v_pk_max_f32 (bit-exact per element).
__device__ __forceinline__ f32x2 fma2(f32x2 a, f32x2 b, f32x2 c) {
    return __builtin_elementwise_fma(a, b, c);
}
__device__ __forceinline__ f32x2 relu2(f32x2 a) {
    f32x2 z = {0.0f, 0.0f};
    return __builtin_elementwise_max(a, z);
}
// Double-bf16 (hi/lo) split of a packed f32 pair. cvt_pk emits the A-frag
// word DIRECTLY (no scalar vector-assembly); float(hi) recovered from the
// packed word with 1 shl + 1 and. Per-element semantics identical to
// x=(__bf16)v; lo=(__bf16)(v-(float)x).
__device__ __forceinline__ void hilo2(f32x2 h, unsigned& hiw, unsigned& low) {
    bf16x2 hb = __builtin_convertvector(h, bf16x2);
    unsigned hw = __builtin_bit_cast(unsigned, hb);
    f32x2 hf;
    hf[0] = __builtin_bit_cast(float, hw << 16);
    hf[1] = __builtin_bit_cast(float, hw & 0xFFFF0000u);
    f32x2 lo = h - hf;
    bf16x2 lb = __builtin_convertvector(lo, bf16x2);
    hiw = hw;
    low = __builtin_bit_cast(unsigned, lb);
}
__device__ __forceinline__ bf16x8 frag4(unsigned w0, unsigned w1, unsigned w2, unsigned w3) {
    uint4 u; u.x = w0; u.y = w1; u.z = w2; u.w = w3;
    return __builtin_bit_cast(bf16x8, u);
}

// NOTE: plain __launch_bounds__(256). The (256,4) variant made the backend cap
// VGPRs at 64 -> ~690 MB/dispatch of scratch spill traffic.
__global__ __launch_bounds__(256) void miniemb_kernel(
    const float* __restrict__ windows,
    const float* __restrict__ W1, const float* __restrict__ b1,
    const float* __restrict__ W2, const float* __restrict__ b2,
    const float* __restrict__ W3, const float* __restrict__ b3,
    float* __restrict__ out)
{
    // LDS total = 24576 + 16384 = 40960 B.
    __shared__ float relbuf[48 * 128];   // XOR-swizzled: word = t*128 + (p ^ (t&31))
    __shared__ uint4 w3lds[16][64];      // W3 B-frags; first 2 KiB doubles as pts4 in ph1-2

    float (*pts4)[4] = reinterpret_cast<float(*)[4]>(&w3lds[0][0]);

    const int m    = blockIdx.x;
    const int tid  = threadIdx.x;
    const int w    = tid >> 6;
    const int lane = tid & 63;
    const int g    = lane >> 4;
    const int ln   = lane & 15;

    // ---- phase 0: stage pts4 (x,y,z,|p|^2) -- W3 fill deferred to after phase 2 ----
    const float* wm = windows + (size_t)m * 128 * 3;
    if (tid < 128) {
        float x = wm[tid * 3], y = wm[tid * 3 + 1], z = wm[tid * 3 + 2];
        float s = __fadd_rn(__fadd_rn(__fmul_rn(x, x), __fmul_rn(y, y)),
                            __fmul_rn(z, z));
        f32x4 P = {x, y, z, s};
        *(f32x4*)&pts4[tid][0] = P;
    }
    __syncthreads();

    // ---- phase 1: kNN scan, 2 threads per point, sorted insert (breadth-wise) ----
    const int k = tid >> 1;      // point
    const int h = tid & 1;       // half
    f32x4 Q = *(const f32x4*)&pts4[k][0];
    u64 bd[16];
    #pragma unroll
    for (int t = 0; t < 16; ++t) bd[t] = ~0ull;
    #pragma unroll 1
    for (int jj = 0; jj < 64; ++jj) {
        const int j = (h << 6) + jj;
        f32x4 P = *(const f32x4*)&pts4[j][0];
        // np-exact d2 (bit-identical to the round-2 proven path)
        float dot = __fadd_rn(__fadd_rn(__fmul_rn(Q.x, P.x),
                                        __fmul_rn(Q.y, P.y)),
                              __fmul_rn(Q.z, P.z));
        float dd = __fsub_rn(__fadd_rn(Q.w, P.w), __fmul_rn(2.0f, dot));
        unsigned u = __float_as_uint(dd);
        unsigned key32 = u ^ (((unsigned)(((int)u) >> 31)) | 0x80000000u);
        u64 kk = ((u64)key32 << 32) | (unsigned)j;
        bool ct[16];
        #pragma unroll
        for (int t = 0; t < 16; ++t) ct[t] = bd[t] < kk;
        #pragma unroll
        for (int t = 15; t >= 1; --t)
            bd[t] = ct[t] ? bd[t] : (ct[t - 1] ? kk : bd[t - 1]);
        bd[0] = ct[0] ? bd[0] : kk;
    }

    // ---- phase 2: lane-pair merge, partner values STREAMED via shuffle ----
    unsigned msk = 0;
    #pragma unroll
    for (int i = 0; i < 16; ++i) {
        u64 o = __shfl_xor(bd[15 - i], 1);   // partner's bd[15-i]
        msk |= (bd[i] < o) ? (1u << i) : 0u;
    }
    const int cnt   = __popc(msk);
    const int rbase = h ? (16 - cnt) : 0;    // A rows: 0..cA-1, B rows: cA..15

    // scale = max norm over selected = sqrt(max d2)  (sqrtf monotone -> bit-identical)
    float m2 = 0.0f;
    #pragma unroll
    for (int i = 0; i < 16; ++i) {
        if (i < cnt) {
            f32x4 P = *(const f32x4*)&pts4[(unsigned)bd[i] & 127u][0];
            float dx = P.x - Q.x, dy = P.y - Q.y, dz = P.z - Q.z;
            m2 = fmaxf(m2, dx * dx + dy * dy + dz * dz);
        }
    }
    m2 = fmaxf(m2, __shfl_xor(m2, 1));
    const float inv = 1.0f / fmaxf(sqrtf(m2), 1e-8f);

    #pragma unroll
    for (int i = 0; i < 16; ++i) {
        if (i < cnt) {
            f32x4 P = *(const f32x4*)&pts4[(unsigned)bd[i] & 127u][0];
            const int t0 = (rbase + i) * 3;
            relbuf[(t0 + 0) * 128 + (k ^ ((t0 + 0) & 31))] = (P.x - Q.x) * inv;
            relbuf[(t0 + 1) * 128 + (k ^ ((t0 + 1) & 31))] = (P.y - Q.y) * inv;
            relbuf[(t0 + 2) * 128 + (k ^ ((t0 + 2) & 31))] = (P.z - Q.z) * inv;
        }
    }
    __syncthreads();   // all pts4 reads done -> safe to overwrite with W3 frags

    // ---- phase 2b: fill w3lds (overwrites the pts4 overlay region) ----
    #pragma unroll
    for (int q = 0; q < 4; ++q) {
        const int f = w * 4 + q, n = f >> 1, kb = f & 1;
        bf16x8 v;
        #pragma unroll
        for (int j = 0; j < 8; ++j)
            v[j] = (__bf16)W3[(kb * 32 + g * 8 + j) * 128 + n * 16 + ln];
        w3lds[f][lane] = __builtin_bit_cast(uint4, v);
    }

    // ---- persistent weight fragments (after kNN: caps register pressure) ----
    bf16x8 w2A[4];
    #pragma unroll
    for (int t = 0; t < 4; ++t) {
        const int c = 32 * (t >> 1) + 8 * (ln >> 2) + 4 * (t & 1) + (ln & 3);
        #pragma unroll
        for (int j = 0; j < 8; ++j)
            w2A[t][j] = (__bf16)W2[(g * 8 + j) * 64 + c];
    }
    float b2p[16];
    #pragma unroll
    for (int t = 0; t < 4; ++t)
        #pragma unroll
        for (int r = 0; r < 4; ++r)
            b2p[t * 4 + r] = b2[32 * (t >> 1) + 8 * g + 4 * (t & 1) + r];
    // W1/b1 as packed f32x2 over column pairs (c = g*8 + 2*jj + e)
    f32x2 w1v0[4], w1v1[4], w1v2[4], b1v[4];
    #pragma unroll
    for (int jj = 0; jj < 4; ++jj) {
        const int c = g * 8 + 2 * jj;
        w1v0[jj] = *(const f32x2*)&W1[c];
        w1v1[jj] = *(const f32x2*)&W1[32 + c];
        w1v2[jj] = *(const f32x2*)&W1[64 + c];
        b1v[jj]  = *(const f32x2*)&b1[c];
    }
    const float b3r0 = b3[(2 * g) * 16 + ln];
    const float b3r1 = b3[(2 * g + 1) * 16 + ln];
    __syncthreads();

    // ---- phase 3: MFMA MLP, 2 points per iteration, packed-fp32 VALU ----
    const float* ra = relbuf + (ln * 3 + 0) * 128;
    const float* rb = relbuf + (ln * 3 + 1) * 128;
    const float* rc = relbuf + (ln * 3 + 2) * 128;
    const int xa = (ln * 3 + 0) & 31;
    const int xb = (ln * 3 + 1) & 31;
    const int xc = (ln * 3 + 2) & 31;

    #pragma unroll 1
    for (int i = 0; i < 16; ++i) {
        const int p0 = w * 32 + 2 * i;
        const int p1 = p0 + 1;
        const float r00 = ra[p0 ^ xa], r01 = rb[p0 ^ xb], r02 = rc[p0 ^ xc];
        const float r10 = ra[p1 ^ xa], r11 = rb[p1 ^ xb], r12 = rc[p1 ^ xc];
        const f32x2 r00v = {r00, r00}, r01v = {r01, r01}, r02v = {r02, r02};
        const f32x2 r10v = {r10, r10}, r11v = {r11, r11}, r12v = {r12, r12};

        // L1 both points: packed over column pairs; cvt_pk words ARE the frags
        unsigned h0w[4], l0w[4], h1w[4], l1w[4];
        #pragma unroll
        for (int jj = 0; jj < 4; ++jj) {
            f32x2 hv0 = fma2(r02v, w1v2[jj], fma2(r01v, w1v1[jj], fma2(r00v, w1v0[jj], b1v[jj])));
            hilo2(relu2(hv0), h0w[jj], l0w[jj]);
            f32x2 hv1 = fma2(r12v, w1v2[jj], fma2(r11v, w1v1[jj], fma2(r10v, w1v0[jj], b1v[jj])));
            hilo2(relu2(hv1), h1w[jj], l1w[jj]);
        }
        bf16x8 a1hi0 = frag4(h0w[0], h0w[1], h0w[2], h0w[3]);
        bf16x8 a1lo0 = frag4(l0w[0], l0w[1], l0w[2], l0w[3]);
        bf16x8 a1hi1 = frag4(h1w[0], h1w[1], h1w[2], h1w[3]);
        bf16x8 a1lo1 = frag4(l1w[0], l1w[1], l1w[2], l1w[3]);

        // L2 transposed, both points
        f32x4 c2_0[4], c2_1[4];
        #pragma unroll
        for (int t = 0; t < 4; ++t) {
            f32x4 acc0 = {b2p[t*4+0], b2p[t*4+1], b2p[t*4+2], b2p[t*4+3]};
            f32x4 acc1 = acc0;
            acc0 = MFMA(w2A[t], a1hi0, acc0);
            acc1 = MFMA(w2A[t], a1hi1, acc1);
            acc0 = MFMA(w2A[t], a1lo0, acc0);
            acc1 = MFMA(w2A[t], a1lo1, acc1);
            c2_0[t] = acc0; c2_1[t] = acc1;
        }

        // relu + hi/lo pack into L3 A-frags (packed pairs; word jj = elems 2jj,2jj+1)
        unsigned ha0[4], la0[4], hb0[4], lb0[4];   // point0: t<2 -> "a", t>=2 -> "b"
        unsigned ha1[4], la1[4], hb1[4], lb1[4];   // point1
        #pragma unroll
        for (int t = 0; t < 2; ++t) {
            f32x2 pA0 = {c2_0[t][0], c2_0[t][1]};
            f32x2 pB0 = {c2_0[t][2], c2_0[t][3]};
            hilo2(relu2(pA0), ha0[2*t],     la0[2*t]);
            hilo2(relu2(pB0), ha0[2*t + 1], la0[2*t + 1]);
            f32x2 pA0b = {c2_0[t+2][0], c2_0[t+2][1]};
            f32x2 pB0b = {c2_0[t+2][2], c2_0[t+2][3]};
            hilo2(relu2(pA0b), hb0[2*t],     lb0[2*t]);
            hilo2(relu2(pB0b), hb0[2*t + 1], lb0[2*t + 1]);
            f32x2 pA1 = {c2_1[t][0], c2_1[t][1]};
            f32x2 pB1 = {c2_1[t][2], c2_1[t][3]};
            hilo2(relu2(pA1), ha1[2*t],     la1[2*t]);
            hilo2(relu2(pB1), ha1[2*t + 1], la1[2*t + 1]);
            f32x2 pA1b = {c2_1[t+2][0], c2_1[t+2][1]};
            f32x2 pB1b = {c2_1[t+2][2], c2_1[t+2][3]};
            hilo2(relu2(pA1b), hb1[2*t],     lb1[2*t]);
            hilo2(relu2(pB1b), hb1[2*t + 1], lb1[2*t + 1]);
        }
        bf16x8 h30a = frag4(ha0[0], ha0[1], ha0[2], ha0[3]);
        bf16x8 l30a = frag4(la0[0], la0[1], la0[2], la0[3]);
        bf16x8 h30b = frag4(hb0[0], hb0[1], hb0[2], hb0[3]);
        bf16x8 l30b = frag4(lb0[0], lb0[1], lb0[2], lb0[3]);
        bf16x8 h31a = frag4(ha1[0], ha1[1], ha1[2], ha1[3]);
        bf16x8 l31a = frag4(la1[0], la1[1], la1[2], la1[3]);
        bf16x8 h31b = frag4(hb1[0], hb1[1], hb1[2], hb1[3]);
        bf16x8 l31b = frag4(lb1[0], lb1[1], lb1[2], lb1[3]);

        // L3: 4 steps x 2 tiles, W3 frags read once, used by both points
        float s0_0 = 0.f, s1_0 = 0.f, s0_1 = 0.f, s1_1 = 0.f;
        #pragma unroll
        for (int nn = 0; nn < 4; ++nn) {
            bf16x8 c0a = __builtin_bit_cast(bf16x8, w3lds[nn * 4 + 0][lane]);
            bf16x8 c0b = __builtin_bit_cast(bf16x8, w3lds[nn * 4 + 1][lane]);
            bf16x8 c1a = __builtin_bit_cast(bf16x8, w3lds[nn * 4 + 2][lane]);
            bf16x8 c1b = __builtin_bit_cast(bf16x8, w3lds[nn * 4 + 3][lane]);
            f32x4 a00 = {0,0,0,0}, a01 = {0,0,0,0}, a10 = {0,0,0,0}, a11 = {0,0,0,0};
            a00 = MFMA(h30a, c0a, a00); a00 = MFMA(h30b, c0b, a00);
            a00 = MFMA(l30a, c0a, a00); a00 = MFMA(l30b, c0b, a00);
            a01 = MFMA(h30a, c1a, a01); a01 = MFMA(h30b, c1b, a01);
            a01 = MFMA(l30a, c1a, a01); a01 = MFMA(l30b, c1b, a01);
            a10 = MFMA(h31a, c0a, a10); a10 = MFMA(h31b, c0b, a10);
            a10 = MFMA(l31a, c0a, a10); a10 = MFMA(l31b, c0b, a10);
            a11 = MFMA(h31a, c1a, a11); a11 = MFMA(h31b, c1b, a11);
            a11 = MFMA(l31a, c1a, a11); a11 = MFMA(l31b, c1b, a11);
            // packed max tree (exact: fp max is assoc/comm for ordered values)
            f32x2 m00 = __builtin_elementwise_max((f32x2){a00[0], a00[1]}, (f32x2){a00[2], a00[3]});
            float v00 = fmaxf(m00[0], m00[1]);
            v00 = fmaxf(v00, __shfl_xor(v00, 16)); v00 = fmaxf(v00, __shfl_xor(v00, 32));
            f32x2 m01 = __builtin_elementwise_max((f32x2){a01[0], a01[1]}, (f32x2){a01[2], a01[3]});
            float v01 = fmaxf(m01[0], m01[1]);
            v01 = fmaxf(v01, __shfl_xor(v01, 16)); v01 = fmaxf(v01, __shfl_xor(v01, 32));
            f32x2 m10 = __builtin_elementwise_max((f32x2){a10[0], a10[1]}, (f32x2){a10[2], a10[3]});
            float v10 = fmaxf(m10[0], m10[1]);
            v10 = fmaxf(v10, __shfl_xor(v10, 16)); v10 = fmaxf(v10, __shfl_xor(v10, 32));
            f32x2 m11 = __builtin_elementwise_max((f32x2){a11[0], a11[1]}, (f32x2){a11[2], a11[3]});
            float v11 = fmaxf(m11[0], m11[1]);
            v11 = fmaxf(v11, __shfl_xor(v11, 16)); v11 = fmaxf(v11, __shfl_xor(v11, 32));
            if (nn == g) { s0_0 = v00; s1_0 = v01; s0_1 = v10; s1_1 = v11; }
        }
        float* o0 = out + ((size_t)(m * 128 + p0) << 7);
        float* o1 = out + ((size_t)(m * 128 + p1) << 7);
        o0[(2 * g) * 16 + ln]     = s0_0 + b3r0;
        o0[(2 * g + 1) * 16 + ln] = s1_0 + b3r1;
        o1[(2 * g) * 16 + ln]     = s0_1 + b3r0;
        o1[(2 * g + 1) * 16 + ln] = s1_1 + b3r1;
    }
}

extern "C" void kernel_launch(void* const* d_in, const int* in_sizes, int n_in,
                              void* d_out, int out_size, void* d_ws, size_t ws_size,
                              hipStream_t stream) {
    const float* windows = (const float*)d_in[0];
    const float* W1 = (const float*)d_in[1];
    const float* b1 = (const float*)d_in[2];
    const float* W2 = (const float*)d_in[3];
    const float* b2 = (const float*)d_in[4];
    const float* W3 = (const float*)d_in[5];
    const float* b3 = (const float*)d_in[6];
    float* out = (float*)d_out;
    hipLaunchKernelGGL(miniemb_kernel, dim3(1024), dim3(256), 0, stream,
                       windows, W1, b1, W2, b2, W3, b3, out);
}